// Round 1
// baseline (672.926 us; speedup 1.0000x reference)
//
#include <hip/hip_runtime.h>

// out[b,s,e] = sum_h cell_states[b,s,e,h] * W[e,h] + bias[e]
// B=4, S=512, E=64, H=1024. N = B*S*E = 131072 rows of length H=1024.
// Rows with the same e (= row_index & 63) share W[e] (4 KiB) and bias[e].
//
// Strategy: persistent waves. Each wave pinned to one e, W[e] cached in 16
// VGPRs + bias once, then strides over its 16 rows for that e,
// FOUR rows per iteration (16 independent 16B loads = 16 KB in flight per
// wave). Plain (temporal) loads: the nt path is the one unverified element
// of the previous kernel, and the harness fills prove the normal path
// sustains 6.4 TB/s. Four interleaved butterfly reductions amortize the
// cross-lane latency chain.

#define H_DIM 1024
#define E_DIM 64

typedef float v4f __attribute__((ext_vector_type(4)));

__device__ __forceinline__ float dot4(v4f a, v4f w) {
    return a.x * w.x + a.y * w.y + a.z * w.z + a.w * w.w;
}

__global__ __launch_bounds__(256) void Cell_to_Entity_78735340470739_kernel(
    const float* __restrict__ x,     // [N, H]
    const float* __restrict__ W,     // [E, H]
    const float* __restrict__ bias,  // [E]
    float* __restrict__ out,         // [N]
    int n_out)
{
    const int lane    = threadIdx.x & 63;
    const int wave    = (int)((blockIdx.x * blockDim.x + threadIdx.x) >> 6);
    const int n_waves = (int)((gridDim.x * blockDim.x) >> 6);

    const int e    = wave & (E_DIM - 1);
    const int step = n_waves >> 6;       // waves sharing this e (128)
    const int r0   = wave >> 6;          // starting row (per-e index)
    const int R    = n_out >> 6;         // rows per e (B*S = 2048)

    // Cache W[e] row in registers, layout matching the x-load pattern.
    const v4f* __restrict__ wp = (const v4f*)(W + (size_t)e * H_DIM);
    const v4f w0 = wp[lane];
    const v4f w1 = wp[lane + 64];
    const v4f w2 = wp[lane + 128];
    const v4f w3 = wp[lane + 192];
    const float be = bias[e];

    int r = r0;
    // Main loop: four rows per iteration -> 16 KB outstanding per wave.
    for (; r + 3 * step < R; r += 4 * step) {
        const int o0 = (r           ) * E_DIM + e;
        const int o1 = (r +     step) * E_DIM + e;
        const int o2 = (r + 2 * step) * E_DIM + e;
        const int o3 = (r + 3 * step) * E_DIM + e;
        const v4f* __restrict__ x0 = (const v4f*)(x + (size_t)o0 * H_DIM);
        const v4f* __restrict__ x1 = (const v4f*)(x + (size_t)o1 * H_DIM);
        const v4f* __restrict__ x2 = (const v4f*)(x + (size_t)o2 * H_DIM);
        const v4f* __restrict__ x3 = (const v4f*)(x + (size_t)o3 * H_DIM);

        // 16 independent 16B loads — issue all before any use.
        const v4f a00 = x0[lane];       const v4f a01 = x0[lane + 64];
        const v4f a02 = x0[lane + 128]; const v4f a03 = x0[lane + 192];
        const v4f a10 = x1[lane];       const v4f a11 = x1[lane + 64];
        const v4f a12 = x1[lane + 128]; const v4f a13 = x1[lane + 192];
        const v4f a20 = x2[lane];       const v4f a21 = x2[lane + 64];
        const v4f a22 = x2[lane + 128]; const v4f a23 = x2[lane + 192];
        const v4f a30 = x3[lane];       const v4f a31 = x3[lane + 64];
        const v4f a32 = x3[lane + 128]; const v4f a33 = x3[lane + 192];

        // Tree-shaped dots: 4-deep chains instead of 16-deep.
        float acc0 = (dot4(a00, w0) + dot4(a01, w1)) + (dot4(a02, w2) + dot4(a03, w3));
        float acc1 = (dot4(a10, w0) + dot4(a11, w1)) + (dot4(a12, w2) + dot4(a13, w3));
        float acc2 = (dot4(a20, w0) + dot4(a21, w1)) + (dot4(a22, w2) + dot4(a23, w3));
        float acc3 = (dot4(a30, w0) + dot4(a31, w1)) + (dot4(a32, w2) + dot4(a33, w3));

        // Four interleaved 64-lane butterfly reductions.
#pragma unroll
        for (int off = 32; off > 0; off >>= 1) {
            acc0 += __shfl_down(acc0, off, 64);
            acc1 += __shfl_down(acc1, off, 64);
            acc2 += __shfl_down(acc2, off, 64);
            acc3 += __shfl_down(acc3, off, 64);
        }
        if (lane == 0) {
            out[o0] = acc0 + be;
            out[o1] = acc1 + be;
            out[o2] = acc2 + be;
            out[o3] = acc3 + be;
        }
    }
    // Tail: single row at a time (not taken for the exact bench shape).
    for (; r < R; r += step) {
        const int o = r * E_DIM + e;
        const v4f* __restrict__ xp = (const v4f*)(x + (size_t)o * H_DIM);
        const v4f a0 = xp[lane];
        const v4f a1 = xp[lane + 64];
        const v4f a2 = xp[lane + 128];
        const v4f a3 = xp[lane + 192];
        float acc = (dot4(a0, w0) + dot4(a1, w1)) + (dot4(a2, w2) + dot4(a3, w3));
#pragma unroll
        for (int off = 32; off > 0; off >>= 1)
            acc += __shfl_down(acc, off, 64);
        if (lane == 0)
            out[o] = acc + be;
    }
}

extern "C" void kernel_launch(void* const* d_in, const int* in_sizes, int n_in,
                              void* d_out, int out_size, void* d_ws, size_t ws_size,
                              hipStream_t stream) {
    const float* x    = (const float*)d_in[0];  // cell_states (B,S,E,H) fp32
    const float* W    = (const float*)d_in[1];  // (E,H) fp32
    const float* bias = (const float*)d_in[2];  // (E,) fp32
    float* out        = (float*)d_out;          // (B,S,E) fp32

    const int n_out = out_size;  // 131072
    // 2048 blocks x 256 threads = 8192 waves = 128 waves per e value.
    // Each wave handles 16 rows = 4 iterations of 4 rows.
    const int blocks = 2048;
    Cell_to_Entity_78735340470739_kernel<<<blocks, 256, 0, stream>>>(
        x, W, bias, out, n_out);
}